// Round 1
// baseline (951.368 us; speedup 1.0000x reference)
//
#include <hip/hip_runtime.h>

#define B_ 16
#define T_ 4096
#define D_ 512
#define L_ 1024
#define NC 8           // T chunks (grid.y)
#define TC (T_ / NC)   // 512 t per chunk
#define BT 128         // t tile per block-iteration
#define BL 128         // l tile per block
#define KK 32          // k chunk staged in LDS

// ---------------- kernel 1: y[b*T+t] = dot(x[b,t,:], fc_w) ----------------
__global__ __launch_bounds__(256) void k_y(const float* __restrict__ x,
                                           const float* __restrict__ w,
                                           float* __restrict__ y) {
    int row  = (blockIdx.x * 256 + threadIdx.x) >> 6;  // one wave per row
    int lane = threadIdx.x & 63;
    const float* r = x + (size_t)row * D_;
    float s = 0.f;
#pragma unroll
    for (int k = 0; k < D_; k += 64) s = fmaf(r[k + lane], w[k + lane], s);
#pragma unroll
    for (int o = 32; o > 0; o >>= 1) s += __shfl_xor(s, o, 64);
    if (lane == 0) y[row] = s;
}

// ---------------- kernel 2: fused score-GEMM + online softmax ----------------
// grid: (L/BL, NC, B), block: 256 threads.
// thread (tx,ty): tid = tx*16 + ty; ty indexes t-subtiles (contiguous lanes so
// the final t-reduction is an in-wave 16-lane butterfly), tx indexes l-subtiles.
__global__ __launch_bounds__(256, 2) void k_main(const float* __restrict__ x,
                                                 const float* __restrict__ q,
                                                 const float* __restrict__ y,
                                                 float* __restrict__ part) {
    __shared__ float Xs[KK][BT + 4];  // k-major, stride 132 floats (16B-aligned rows)
    __shared__ float Qs[KK][BL + 4];

    const int tid   = threadIdx.x;
    const int ty    = tid & 15;
    const int tx    = tid >> 4;
    const int lb    = blockIdx.x * BL;
    const int chunk = blockIdx.y;
    const int b     = blockIdx.z;

    const int g  = tid & 7;   // k-group (float4) for staging
    const int r0 = tid >> 3;  // staging row 0..31

    float run_m[8], run_z[8], run_n[8];
#pragma unroll
    for (int j = 0; j < 8; ++j) { run_m[j] = -1e30f; run_z[j] = 0.f; run_n[j] = 0.f; }

    for (int tt = 0; tt < TC; tt += BT) {
        const int t0 = chunk * TC + tt;

        float s[8][8];
#pragma unroll
        for (int i = 0; i < 8; ++i)
#pragma unroll
            for (int j = 0; j < 8; ++j) s[i][j] = 0.f;

        for (int kc = 0; kc < D_; kc += KK) {
            __syncthreads();  // previous compute done before overwrite
#pragma unroll
            for (int p = 0; p < 4; ++p) {
                int rr = p * 32 + r0;
                float4 vx = *(const float4*)(x + ((size_t)b * T_ + t0 + rr) * D_ + kc + g * 4);
                float4 vq = *(const float4*)(q + (size_t)(lb + rr) * D_ + kc + g * 4);
                Xs[g * 4 + 0][rr] = vx.x; Xs[g * 4 + 1][rr] = vx.y;
                Xs[g * 4 + 2][rr] = vx.z; Xs[g * 4 + 3][rr] = vx.w;
                Qs[g * 4 + 0][rr] = vq.x; Qs[g * 4 + 1][rr] = vq.y;
                Qs[g * 4 + 2][rr] = vq.z; Qs[g * 4 + 3][rr] = vq.w;
            }
            __syncthreads();  // staging visible
#pragma unroll
            for (int k = 0; k < KK; ++k) {
                float4 a0 = *(const float4*)&Xs[k][ty * 4];
                float4 a1 = *(const float4*)&Xs[k][64 + ty * 4];
                float4 b0 = *(const float4*)&Qs[k][tx * 4];
                float4 b1 = *(const float4*)&Qs[k][64 + tx * 4];
                float av[8] = {a0.x, a0.y, a0.z, a0.w, a1.x, a1.y, a1.z, a1.w};
                float bv[8] = {b0.x, b0.y, b0.z, b0.w, b1.x, b1.y, b1.z, b1.w};
#pragma unroll
                for (int i = 0; i < 8; ++i)
#pragma unroll
                    for (int j = 0; j < 8; ++j)
                        s[i][j] = fmaf(av[i], bv[j], s[i][j]);
            }
        }

        // epilogue: fold this t-tile into per-lane running softmax state
        float yv[8];
#pragma unroll
        for (int i = 0; i < 8; ++i) {
            int tl = (i < 4) ? (ty * 4 + i) : (64 + ty * 4 + (i - 4));
            yv[i] = y[(size_t)b * T_ + t0 + tl];
        }
#pragma unroll
        for (int j = 0; j < 8; ++j) {
            float mt = s[0][j];
#pragma unroll
            for (int i = 1; i < 8; ++i) mt = fmaxf(mt, s[i][j]);
            float mn = fmaxf(run_m[j], mt);
            float sc = __expf(run_m[j] - mn);
            float z = run_z[j] * sc;
            float n = run_n[j] * sc;
#pragma unroll
            for (int i = 0; i < 8; ++i) {
                float p = __expf(s[i][j] - mn);
                z += p;
                n = fmaf(p, yv[i], n);
            }
            run_m[j] = mn; run_z[j] = z; run_n[j] = n;
        }
    }

    // merge the 16 ty-lanes' partial states (in-wave butterfly)
#pragma unroll
    for (int msk = 1; msk < 16; msk <<= 1) {
#pragma unroll
        for (int j = 0; j < 8; ++j) {
            float om = __shfl_xor(run_m[j], msk, 64);
            float oz = __shfl_xor(run_z[j], msk, 64);
            float on = __shfl_xor(run_n[j], msk, 64);
            float mn = fmaxf(run_m[j], om);
            float s0 = __expf(run_m[j] - mn);
            float s1 = __expf(om - mn);
            run_z[j] = fmaf(run_z[j], s0, oz * s1);
            run_n[j] = fmaf(run_n[j], s0, on * s1);
            run_m[j] = mn;
        }
    }

    if (ty == 0) {
#pragma unroll
        for (int j = 0; j < 8; ++j) {
            int ll = (j < 4) ? (tx * 4 + j) : (64 + tx * 4 + (j - 4));
            size_t idx = ((size_t)(b * L_ + lb + ll) * NC + chunk) * 3;
            part[idx + 0] = run_m[j];
            part[idx + 1] = run_z[j];
            part[idx + 2] = run_n[j];
        }
    }
}

// ---------------- kernel 3: combine chunk partials ----------------
__global__ __launch_bounds__(256) void k_comb(const float* __restrict__ part,
                                              const float* __restrict__ fc_b,
                                              float* __restrict__ out) {
    int bl = blockIdx.x * 256 + threadIdx.x;  // b*L + l
    float m = -1e30f, z = 0.f, n = 0.f;
#pragma unroll
    for (int c = 0; c < NC; ++c) {
        size_t idx = ((size_t)bl * NC + c) * 3;
        float pm = part[idx + 0], pz = part[idx + 1], pn = part[idx + 2];
        float mn = fmaxf(m, pm);
        float s0 = __expf(m - mn), s1 = __expf(pm - mn);
        z = fmaf(z, s0, pz * s1);
        n = fmaf(n, s0, pn * s1);
        m = mn;
    }
    out[bl] = n / z + fc_b[0];
}

extern "C" void kernel_launch(void* const* d_in, const int* in_sizes, int n_in,
                              void* d_out, int out_size, void* d_ws, size_t ws_size,
                              hipStream_t stream) {
    const float* x    = (const float*)d_in[0];  // (B,T,D)
    const float* q    = (const float*)d_in[1];  // (L,D)
    const float* fc_w = (const float*)d_in[2];  // (1,D)
    const float* fc_b = (const float*)d_in[3];  // (1,)
    float* out  = (float*)d_out;                // (B,L)
    float* y    = (float*)d_ws;                 // B*T floats
    float* part = y + (size_t)B_ * T_;          // B*L*NC*3 floats

    k_y<<<B_ * T_ / 4, 256, 0, stream>>>(x, fc_w, y);
    k_main<<<dim3(L_ / BL, NC, B_), 256, 0, stream>>>(x, q, y, part);
    k_comb<<<B_ * L_ / 256, 256, 0, stream>>>(part, fc_b, out);
}

// Round 2
// 325.381 us; speedup vs baseline: 2.9239x; 2.9239x over previous
//
#include <hip/hip_runtime.h>

#define B_ 16
#define T_ 4096
#define D_ 512
#define L_ 1024
#define NTCH (T_ / 64)   // 64 t-chunks for fp16-path partials

typedef _Float16 half8 __attribute__((ext_vector_type(8)));
typedef float float4v __attribute__((ext_vector_type(4)));

// async global->LDS, 16B per lane; LDS dest = uniform base + lane*16
__device__ inline void gl_lds(const void* g, void* l) {
    __builtin_amdgcn_global_load_lds(
        (const __attribute__((address_space(1))) unsigned int*)g,
        (__attribute__((address_space(3))) unsigned int*)l, 16, 0, 0);
}

// ---------------- k_y: y[row] = dot(x[row,:], fc_w) ----------------
__global__ __launch_bounds__(256) void k_y(const float* __restrict__ x,
                                           const float* __restrict__ w,
                                           float* __restrict__ y) {
    int row  = (blockIdx.x * 256 + threadIdx.x) >> 6;
    int lane = threadIdx.x & 63;
    const float* r = x + (size_t)row * D_;
    float s = 0.f;
#pragma unroll
    for (int k = 0; k < D_; k += 64) s = fmaf(r[k + lane], w[k + lane], s);
#pragma unroll
    for (int o = 32; o > 0; o >>= 1) s += __shfl_xor(s, o, 64);
    if (lane == 0) y[row] = s;
}

// ---------------- k_cvt: fp32 (rows x D) -> fp16 fragment-order ----------------
// layout: 1KB blocks [row16-block][k32-chunk]; within block, half8 index =
// (row&15) + 16*((k&31)>>3), elems = k&7.  Matches MFMA A/B operand order.
__global__ __launch_bounds__(256) void k_cvt(const float* __restrict__ src,
                                             _Float16* __restrict__ dst) {
    int idx = blockIdx.x * 256 + threadIdx.x;
    int g   = idx & 63;   // which 8-k group
    int row = idx >> 6;
    const float* p = src + (size_t)row * D_ + g * 8;
    float4 a = *(const float4*)p;
    float4 c = *(const float4*)(p + 4);
    half8 h;
    h[0] = (_Float16)a.x; h[1] = (_Float16)a.y; h[2] = (_Float16)a.z; h[3] = (_Float16)a.w;
    h[4] = (_Float16)c.x; h[5] = (_Float16)c.y; h[6] = (_Float16)c.z; h[7] = (_Float16)c.w;
    size_t blk = (size_t)(row >> 4) * (D_ / 32) + (g >> 2);
    ((half8*)dst)[blk * 64 + (row & 15) + 16 * (g & 3)] = h;
}

// ---------------- k_mfma: fused fp16 score-GEMM + online softmax ----------------
// grid (L/128, T/128, B), 256 threads = 4 waves; wave w -> 64x64 quadrant
// (t-half = w>>1, l-half = w&1). Partials per (b,l,64-t-chunk) -> part.
__global__ __launch_bounds__(256, 2) void k_mfma(const _Float16* __restrict__ xt,
                                                 const _Float16* __restrict__ qt,
                                                 const float* __restrict__ y,
                                                 float* __restrict__ part) {
    __shared__ half8 S[1024];   // [0,512): x tile (8 t16-blocks), [512,1024): q tile
    __shared__ float ys[128];

    const int tid  = threadIdx.x;
    const int lane = tid & 63;
    const int w    = tid >> 6;
    const int b    = blockIdx.z;
    const int tb0  = b * (T_ / 16) + blockIdx.y * 8;  // global 16-row block base (x)
    const int lb0  = blockIdx.x * 8;                  // 16-row block base (q)

    if (tid < 128) ys[tid] = y[(size_t)b * T_ + blockIdx.y * 128 + tid];

    float4v acc[4][4];
#pragma unroll
    for (int i = 0; i < 4; ++i)
#pragma unroll
        for (int j = 0; j < 4; ++j) acc[i][j] = (float4v){0.f, 0.f, 0.f, 0.f};

    const half8* Xg = (const half8*)xt;
    const half8* Qg = (const half8*)qt;
    const int xa = tb0 + 2 * w;   // this wave's two x staging blocks
    const int qa = lb0 + 2 * w;
    const int ts = (w >> 1) * 4, ls = (w & 1) * 4;

    for (int kc = 0; kc < D_ / 32; ++kc) {
        __syncthreads();  // previous chunk's reads done
        gl_lds(Xg + ((size_t)xa * (D_ / 32) + kc) * 64 + lane,       &S[(2 * w) * 64]);
        gl_lds(Xg + ((size_t)(xa + 1) * (D_ / 32) + kc) * 64 + lane, &S[(2 * w + 1) * 64]);
        gl_lds(Qg + ((size_t)qa * (D_ / 32) + kc) * 64 + lane,       &S[512 + (2 * w) * 64]);
        gl_lds(Qg + ((size_t)(qa + 1) * (D_ / 32) + kc) * 64 + lane, &S[512 + (2 * w + 1) * 64]);
        __syncthreads();  // staging visible

        half8 A[4], Bv[4];
#pragma unroll
        for (int i = 0; i < 4; ++i) A[i] = S[(ts + i) * 64 + lane];
#pragma unroll
        for (int j = 0; j < 4; ++j) Bv[j] = S[512 + (ls + j) * 64 + lane];
#pragma unroll
        for (int i = 0; i < 4; ++i)
#pragma unroll
            for (int j = 0; j < 4; ++j)
                acc[i][j] = __builtin_amdgcn_mfma_f32_16x16x32_f16(A[i], Bv[j], acc[i][j], 0, 0, 0);
    }

    // epilogue: online softmax over this wave's 64 t, per l column
    const int quad = lane >> 4, cl = lane & 15;
    const int tw = (w >> 1) * 64;                  // t offset within block's 128
    const int tchunk = blockIdx.y * 2 + (w >> 1);  // 64-t chunk id
    const int lbase = blockIdx.x * 128 + (w & 1) * 64;

#pragma unroll
    for (int j = 0; j < 4; ++j) {
        float m = -1e30f;
#pragma unroll
        for (int i = 0; i < 4; ++i)
#pragma unroll
            for (int r = 0; r < 4; ++r) m = fmaxf(m, acc[i][j][r]);
        float z = 0.f, n = 0.f;
#pragma unroll
        for (int i = 0; i < 4; ++i)
#pragma unroll
            for (int r = 0; r < 4; ++r) {
                float p = __expf(acc[i][j][r] - m);
                z += p;
                n = fmaf(p, ys[tw + i * 16 + quad * 4 + r], n);
            }
#pragma unroll
        for (int msk = 16; msk <= 32; msk <<= 1) {
            float om = __shfl_xor(m, msk, 64);
            float oz = __shfl_xor(z, msk, 64);
            float on = __shfl_xor(n, msk, 64);
            float mn = fmaxf(m, om);
            float s0 = __expf(m - mn), s1 = __expf(om - mn);
            z = fmaf(z, s0, oz * s1);
            n = fmaf(n, s0, on * s1);
            m = mn;
        }
        if (quad == 0) {
            int l = lbase + j * 16 + cl;
            size_t idx = ((size_t)(b * L_ + l) * NTCH + tchunk) * 3;
            part[idx + 0] = m;
            part[idx + 1] = z;
            part[idx + 2] = n;
        }
    }
}

// ---------------- fallback fp32 path (round-1 k_main) ----------------
#define NC 8
#define TC (T_ / NC)
#define BT 128
#define BL 128
#define KK 32

__global__ __launch_bounds__(256, 2) void k_main(const float* __restrict__ x,
                                                 const float* __restrict__ q,
                                                 const float* __restrict__ y,
                                                 float* __restrict__ part) {
    __shared__ float Xs[KK][BT + 4];
    __shared__ float Qs[KK][BL + 4];
    const int tid = threadIdx.x;
    const int ty = tid & 15, tx = tid >> 4;
    const int lb = blockIdx.x * BL, chunk = blockIdx.y, b = blockIdx.z;
    const int g = tid & 7, r0 = tid >> 3;

    float run_m[8], run_z[8], run_n[8];
#pragma unroll
    for (int j = 0; j < 8; ++j) { run_m[j] = -1e30f; run_z[j] = 0.f; run_n[j] = 0.f; }

    for (int tt = 0; tt < TC; tt += BT) {
        const int t0 = chunk * TC + tt;
        float s[8][8];
#pragma unroll
        for (int i = 0; i < 8; ++i)
#pragma unroll
            for (int j = 0; j < 8; ++j) s[i][j] = 0.f;
        for (int kc = 0; kc < D_; kc += KK) {
            __syncthreads();
#pragma unroll
            for (int p = 0; p < 4; ++p) {
                int rr = p * 32 + r0;
                float4 vx = *(const float4*)(x + ((size_t)b * T_ + t0 + rr) * D_ + kc + g * 4);
                float4 vq = *(const float4*)(q + (size_t)(lb + rr) * D_ + kc + g * 4);
                Xs[g * 4 + 0][rr] = vx.x; Xs[g * 4 + 1][rr] = vx.y;
                Xs[g * 4 + 2][rr] = vx.z; Xs[g * 4 + 3][rr] = vx.w;
                Qs[g * 4 + 0][rr] = vq.x; Qs[g * 4 + 1][rr] = vq.y;
                Qs[g * 4 + 2][rr] = vq.z; Qs[g * 4 + 3][rr] = vq.w;
            }
            __syncthreads();
#pragma unroll
            for (int k = 0; k < KK; ++k) {
                float4 a0 = *(const float4*)&Xs[k][ty * 4];
                float4 a1 = *(const float4*)&Xs[k][64 + ty * 4];
                float4 b0 = *(const float4*)&Qs[k][tx * 4];
                float4 b1 = *(const float4*)&Qs[k][64 + tx * 4];
                float av[8] = {a0.x, a0.y, a0.z, a0.w, a1.x, a1.y, a1.z, a1.w};
                float bv[8] = {b0.x, b0.y, b0.z, b0.w, b1.x, b1.y, b1.z, b1.w};
#pragma unroll
                for (int i = 0; i < 8; ++i)
#pragma unroll
                    for (int j = 0; j < 8; ++j) s[i][j] = fmaf(av[i], bv[j], s[i][j]);
            }
        }
        float yv[8];
#pragma unroll
        for (int i = 0; i < 8; ++i) {
            int tl = (i < 4) ? (ty * 4 + i) : (64 + ty * 4 + (i - 4));
            yv[i] = y[(size_t)b * T_ + t0 + tl];
        }
#pragma unroll
        for (int j = 0; j < 8; ++j) {
            float mt = s[0][j];
#pragma unroll
            for (int i = 1; i < 8; ++i) mt = fmaxf(mt, s[i][j]);
            float mn = fmaxf(run_m[j], mt);
            float sc = __expf(run_m[j] - mn);
            float z = run_z[j] * sc, n = run_n[j] * sc;
#pragma unroll
            for (int i = 0; i < 8; ++i) {
                float p = __expf(s[i][j] - mn);
                z += p;
                n = fmaf(p, yv[i], n);
            }
            run_m[j] = mn; run_z[j] = z; run_n[j] = n;
        }
    }
#pragma unroll
    for (int msk = 1; msk < 16; msk <<= 1) {
#pragma unroll
        for (int j = 0; j < 8; ++j) {
            float om = __shfl_xor(run_m[j], msk, 64);
            float oz = __shfl_xor(run_z[j], msk, 64);
            float on = __shfl_xor(run_n[j], msk, 64);
            float mn = fmaxf(run_m[j], om);
            float s0 = __expf(run_m[j] - mn), s1 = __expf(om - mn);
            run_z[j] = fmaf(run_z[j], s0, oz * s1);
            run_n[j] = fmaf(run_n[j], s0, on * s1);
            run_m[j] = mn;
        }
    }
    if (ty == 0) {
#pragma unroll
        for (int j = 0; j < 8; ++j) {
            int ll = (j < 4) ? (tx * 4 + j) : (64 + tx * 4 + (j - 4));
            size_t idx = ((size_t)(b * L_ + lb + ll) * NC + chunk) * 3;
            part[idx + 0] = run_m[j];
            part[idx + 1] = run_z[j];
            part[idx + 2] = run_n[j];
        }
    }
}

// ---------------- combine partials (nc runtime) ----------------
__global__ __launch_bounds__(256) void k_comb(const float* __restrict__ part,
                                              const float* __restrict__ fc_b,
                                              float* __restrict__ out, int nc) {
    int bl = blockIdx.x * 256 + threadIdx.x;
    float m = -1e30f, z = 0.f, n = 0.f;
    for (int c = 0; c < nc; ++c) {
        size_t idx = ((size_t)bl * nc + c) * 3;
        float pm = part[idx + 0], pz = part[idx + 1], pn = part[idx + 2];
        float mn = fmaxf(m, pm);
        float s0 = __expf(m - mn), s1 = __expf(pm - mn);
        z = fmaf(z, s0, pz * s1);
        n = fmaf(n, s0, pn * s1);
        m = mn;
    }
    out[bl] = n / z + fc_b[0];
}

extern "C" void kernel_launch(void* const* d_in, const int* in_sizes, int n_in,
                              void* d_out, int out_size, void* d_ws, size_t ws_size,
                              hipStream_t stream) {
    const float* x    = (const float*)d_in[0];
    const float* q    = (const float*)d_in[1];
    const float* fc_w = (const float*)d_in[2];
    const float* fc_b = (const float*)d_in[3];
    float* out = (float*)d_out;
    float* ws  = (float*)d_ws;

    const size_t Y_F    = (size_t)B_ * T_;              // 65536 floats
    const size_t PART_F = (size_t)B_ * L_ * NTCH * 3;   // 3,145,728 floats
    const size_t XT_H   = (size_t)B_ * T_ * D_;         // halfs
    const size_t QT_H   = (size_t)L_ * D_;              // halfs
    const size_t need   = (Y_F + PART_F) * 4 + (XT_H + QT_H) * 2;

    if (ws_size >= need) {
        float* y    = ws;
        float* part = ws + Y_F;
        _Float16* xt = (_Float16*)(ws + Y_F + PART_F);
        _Float16* qt = xt + XT_H;
        k_y  <<<B_ * T_ / 4, 256, 0, stream>>>(x, fc_w, y);
        k_cvt<<<(B_ * T_ * 64) / 256, 256, 0, stream>>>(x, xt);
        k_cvt<<<(L_ * 64) / 256, 256, 0, stream>>>(q, qt);
        k_mfma<<<dim3(L_ / 128, T_ / 128, B_), 256, 0, stream>>>(xt, qt, y, part);
        k_comb<<<B_ * L_ / 256, 256, 0, stream>>>(part, fc_b, out, NTCH);
    } else {
        float* y    = ws;
        float* part = ws + Y_F;
        k_y   <<<B_ * T_ / 4, 256, 0, stream>>>(x, fc_w, y);
        k_main<<<dim3(L_ / BL, NC, B_), 256, 0, stream>>>(x, q, y, part);
        k_comb<<<B_ * L_ / 256, 256, 0, stream>>>(part, fc_b, out, NC);
    }
}

// Round 3
// 301.517 us; speedup vs baseline: 3.1553x; 1.0791x over previous
//
#include <hip/hip_runtime.h>

#define B_ 16
#define T_ 4096
#define D_ 512
#define L_ 1024
#define NTCH (T_ / 64)   // 64 t-chunks for fp16-path partials

typedef _Float16 half8 __attribute__((ext_vector_type(8)));
typedef float float4v __attribute__((ext_vector_type(4)));

// async global->LDS, 16B per lane; LDS dest = uniform base + lane*16
__device__ inline void gl_lds(const void* g, void* l) {
    __builtin_amdgcn_global_load_lds(
        (const __attribute__((address_space(1))) unsigned int*)g,
        (__attribute__((address_space(3))) unsigned int*)l, 16, 0, 0);
}

// ---------------- k_y (fallback path only) ----------------
__global__ __launch_bounds__(256) void k_y(const float* __restrict__ x,
                                           const float* __restrict__ w,
                                           float* __restrict__ y) {
    int row  = (blockIdx.x * 256 + threadIdx.x) >> 6;
    int lane = threadIdx.x & 63;
    const float* r = x + (size_t)row * D_;
    float s = 0.f;
#pragma unroll
    for (int k = 0; k < D_; k += 64) s = fmaf(r[k + lane], w[k + lane], s);
#pragma unroll
    for (int o = 32; o > 0; o >>= 1) s += __shfl_xor(s, o, 64);
    if (lane == 0) y[row] = s;
}

// ---------------- k_prep: fused y + fp32->fp16 fragment-order convert ----------------
// One block per 16-row block of x. Coalesced global reads -> LDS; y computed
// from LDS (bank-staggered); fp16 written in MFMA fragment order with each
// wave storing a contiguous 1KB run (fully coalesced).
__global__ __launch_bounds__(256) void k_prep(const float* __restrict__ x,
                                              const float* __restrict__ w,
                                              _Float16* __restrict__ xt,
                                              float* __restrict__ y) {
    __shared__ float Xl[16 * 512];
    __shared__ float wl[512];
    const int tid = threadIdx.x;
    const size_t base = (size_t)blockIdx.x * (16 * 512);

    if (tid < 128) ((float4*)wl)[tid] = ((const float4*)w)[tid];
#pragma unroll
    for (int it = 0; it < 8; ++it) {
        int f = it * 1024 + tid * 4;
        ((float4*)Xl)[f >> 2] = *(const float4*)(x + base + f);
    }
    __syncthreads();

    // y: thread (row=tid>>4, seg=tid&15) reduces 32 floats, staggered to avoid
    // bank conflicts ((j+tid)&31 -> 2-way, free). 16-lane shuffle reduce.
    {
        int row = tid >> 4, seg = tid & 15;
        float p = 0.f;
#pragma unroll
        for (int j = 0; j < 32; ++j) {
            int k = seg * 32 + ((j + tid) & 31);
            p = fmaf(Xl[row * 512 + k], wl[k], p);
        }
        p += __shfl_xor(p, 1, 64); p += __shfl_xor(p, 2, 64);
        p += __shfl_xor(p, 4, 64); p += __shfl_xor(p, 8, 64);
        if (seg == 0) y[blockIdx.x * 16 + row] = p;
    }

    // convert: wave handles kc-blocks; lane idx -> (row=idx&15, gq=idx>>4);
    // output half8[kc*64 + idx] contiguous per wave.
    {
        int idx = tid & 63, row = idx & 15, gq = idx >> 4;
        half8* dst = (half8*)xt + (size_t)blockIdx.x * (D_ / 32) * 64;
#pragma unroll
        for (int it2 = 0; it2 < 4; ++it2) {
            int kc = it2 * 4 + (tid >> 6);
            int k0 = kc * 32 + gq * 8;
            float4 a = *(float4*)&Xl[row * 512 + k0];
            float4 c = *(float4*)&Xl[row * 512 + k0 + 4];
            half8 h;
            h[0] = (_Float16)a.x; h[1] = (_Float16)a.y; h[2] = (_Float16)a.z; h[3] = (_Float16)a.w;
            h[4] = (_Float16)c.x; h[5] = (_Float16)c.y; h[6] = (_Float16)c.z; h[7] = (_Float16)c.w;
            dst[kc * 64 + idx] = h;
        }
    }
}

// ---------------- k_cvt: q fp32 -> fp16 fragment-order (small) ----------------
__global__ __launch_bounds__(256) void k_cvt(const float* __restrict__ src,
                                             _Float16* __restrict__ dst) {
    int idx = blockIdx.x * 256 + threadIdx.x;
    int g   = idx & 63;
    int row = idx >> 6;
    const float* p = src + (size_t)row * D_ + g * 8;
    float4 a = *(const float4*)p;
    float4 c = *(const float4*)(p + 4);
    half8 h;
    h[0] = (_Float16)a.x; h[1] = (_Float16)a.y; h[2] = (_Float16)a.z; h[3] = (_Float16)a.w;
    h[4] = (_Float16)c.x; h[5] = (_Float16)c.y; h[6] = (_Float16)c.z; h[7] = (_Float16)c.w;
    size_t blk = (size_t)(row >> 4) * (D_ / 32) + (g >> 2);
    ((half8*)dst)[blk * 64 + (row & 15) + 16 * (g & 3)] = h;
}

// ---------------- k_mfma: fused fp16 score-GEMM + online softmax ----------------
// 1-D grid 4096, XCD-swizzled: bid&7 = XCD (dispatch round-robin); all 8
// l-blocks of a (b,t)-tile land on one XCD -> xt tile fetched into one L2.
__global__ __launch_bounds__(256, 4) void k_mfma(const _Float16* __restrict__ xt,
                                                 const _Float16* __restrict__ qt,
                                                 const float* __restrict__ y,
                                                 float* __restrict__ part) {
    __shared__ half8 S[1024];   // [0,512): x tile, [512,1024): q tile
    __shared__ float ys[128];

    const int bid  = blockIdx.x;
    const int xcd  = bid & 7;
    const int jj   = bid >> 3;
    const int tile = (xcd << 6) | (jj >> 3);   // 512 (b,t) tiles, 64 per XCD
    const int lblk = jj & 7;
    const int tblk = tile & 31;
    const int b    = tile >> 5;

    const int tid  = threadIdx.x;
    const int lane = tid & 63;
    const int w    = tid >> 6;
    const int tb0  = b * (T_ / 16) + tblk * 8;  // 16-row block base (x)
    const int lb0  = lblk * 8;                  // 16-row block base (q)

    if (tid < 128) ys[tid] = y[(size_t)b * T_ + tblk * 128 + tid];

    float4v acc[4][4];
#pragma unroll
    for (int i = 0; i < 4; ++i)
#pragma unroll
        for (int j = 0; j < 4; ++j) acc[i][j] = (float4v){0.f, 0.f, 0.f, 0.f};

    const half8* Xg = (const half8*)xt;
    const half8* Qg = (const half8*)qt;
    const int xa = tb0 + 2 * w;
    const int qa = lb0 + 2 * w;
    const int ts = (w >> 1) * 4, ls = (w & 1) * 4;

    for (int kc = 0; kc < D_ / 32; ++kc) {
        __syncthreads();
        gl_lds(Xg + ((size_t)xa * (D_ / 32) + kc) * 64 + lane,       &S[(2 * w) * 64]);
        gl_lds(Xg + ((size_t)(xa + 1) * (D_ / 32) + kc) * 64 + lane, &S[(2 * w + 1) * 64]);
        gl_lds(Qg + ((size_t)qa * (D_ / 32) + kc) * 64 + lane,       &S[512 + (2 * w) * 64]);
        gl_lds(Qg + ((size_t)(qa + 1) * (D_ / 32) + kc) * 64 + lane, &S[512 + (2 * w + 1) * 64]);
        __syncthreads();

        half8 A[4], Bv[4];
#pragma unroll
        for (int i = 0; i < 4; ++i) A[i] = S[(ts + i) * 64 + lane];
#pragma unroll
        for (int j = 0; j < 4; ++j) Bv[j] = S[512 + (ls + j) * 64 + lane];
#pragma unroll
        for (int i = 0; i < 4; ++i)
#pragma unroll
            for (int j = 0; j < 4; ++j)
                acc[i][j] = __builtin_amdgcn_mfma_f32_16x16x32_f16(A[i], Bv[j], acc[i][j], 0, 0, 0);
    }

    const int quad = lane >> 4, cl = lane & 15;
    const int tw = (w >> 1) * 64;
    const int tchunk = tblk * 2 + (w >> 1);
    const int lbase = lblk * 128 + (w & 1) * 64;

#pragma unroll
    for (int j = 0; j < 4; ++j) {
        float m = -1e30f;
#pragma unroll
        for (int i = 0; i < 4; ++i)
#pragma unroll
            for (int r = 0; r < 4; ++r) m = fmaxf(m, acc[i][j][r]);
        float z = 0.f, n = 0.f;
#pragma unroll
        for (int i = 0; i < 4; ++i)
#pragma unroll
            for (int r = 0; r < 4; ++r) {
                float p = __expf(acc[i][j][r] - m);
                z += p;
                n = fmaf(p, ys[tw + i * 16 + quad * 4 + r], n);
            }
#pragma unroll
        for (int msk = 16; msk <= 32; msk <<= 1) {
            float om = __shfl_xor(m, msk, 64);
            float oz = __shfl_xor(z, msk, 64);
            float on = __shfl_xor(n, msk, 64);
            float mn = fmaxf(m, om);
            float s0 = __expf(m - mn), s1 = __expf(om - mn);
            z = fmaf(z, s0, oz * s1);
            n = fmaf(n, s0, on * s1);
            m = mn;
        }
        if (quad == 0) {
            int l = lbase + j * 16 + cl;
            size_t idx = ((size_t)(b * L_ + l) * NTCH + tchunk) * 3;
            part[idx + 0] = m;
            part[idx + 1] = z;
            part[idx + 2] = n;
        }
    }
}

// ---------------- fallback fp32 path (round-1 k_main) ----------------
#define NC 8
#define TC (T_ / NC)
#define BT 128
#define BL 128
#define KK 32

__global__ __launch_bounds__(256, 2) void k_main(const float* __restrict__ x,
                                                 const float* __restrict__ q,
                                                 const float* __restrict__ y,
                                                 float* __restrict__ part) {
    __shared__ float Xs[KK][BT + 4];
    __shared__ float Qs[KK][BL + 4];
    const int tid = threadIdx.x;
    const int ty = tid & 15, tx = tid >> 4;
    const int lb = blockIdx.x * BL, chunk = blockIdx.y, b = blockIdx.z;
    const int g = tid & 7, r0 = tid >> 3;

    float run_m[8], run_z[8], run_n[8];
#pragma unroll
    for (int j = 0; j < 8; ++j) { run_m[j] = -1e30f; run_z[j] = 0.f; run_n[j] = 0.f; }

    for (int tt = 0; tt < TC; tt += BT) {
        const int t0 = chunk * TC + tt;
        float s[8][8];
#pragma unroll
        for (int i = 0; i < 8; ++i)
#pragma unroll
            for (int j = 0; j < 8; ++j) s[i][j] = 0.f;
        for (int kc = 0; kc < D_; kc += KK) {
            __syncthreads();
#pragma unroll
            for (int p = 0; p < 4; ++p) {
                int rr = p * 32 + r0;
                float4 vx = *(const float4*)(x + ((size_t)b * T_ + t0 + rr) * D_ + kc + g * 4);
                float4 vq = *(const float4*)(q + (size_t)(lb + rr) * D_ + kc + g * 4);
                Xs[g * 4 + 0][rr] = vx.x; Xs[g * 4 + 1][rr] = vx.y;
                Xs[g * 4 + 2][rr] = vx.z; Xs[g * 4 + 3][rr] = vx.w;
                Qs[g * 4 + 0][rr] = vq.x; Qs[g * 4 + 1][rr] = vq.y;
                Qs[g * 4 + 2][rr] = vq.z; Qs[g * 4 + 3][rr] = vq.w;
            }
            __syncthreads();
#pragma unroll
            for (int k = 0; k < KK; ++k) {
                float4 a0 = *(const float4*)&Xs[k][ty * 4];
                float4 a1 = *(const float4*)&Xs[k][64 + ty * 4];
                float4 b0 = *(const float4*)&Qs[k][tx * 4];
                float4 b1 = *(const float4*)&Qs[k][64 + tx * 4];
                float av[8] = {a0.x, a0.y, a0.z, a0.w, a1.x, a1.y, a1.z, a1.w};
                float bv[8] = {b0.x, b0.y, b0.z, b0.w, b1.x, b1.y, b1.z, b1.w};
#pragma unroll
                for (int i = 0; i < 8; ++i)
#pragma unroll
                    for (int j = 0; j < 8; ++j) s[i][j] = fmaf(av[i], bv[j], s[i][j]);
            }
        }
        float yv[8];
#pragma unroll
        for (int i = 0; i < 8; ++i) {
            int tl = (i < 4) ? (ty * 4 + i) : (64 + ty * 4 + (i - 4));
            yv[i] = y[(size_t)b * T_ + t0 + tl];
        }
#pragma unroll
        for (int j = 0; j < 8; ++j) {
            float mt = s[0][j];
#pragma unroll
            for (int i = 1; i < 8; ++i) mt = fmaxf(mt, s[i][j]);
            float mn = fmaxf(run_m[j], mt);
            float sc = __expf(run_m[j] - mn);
            float z = run_z[j] * sc, n = run_n[j] * sc;
#pragma unroll
            for (int i = 0; i < 8; ++i) {
                float p = __expf(s[i][j] - mn);
                z += p;
                n = fmaf(p, yv[i], n);
            }
            run_m[j] = mn; run_z[j] = z; run_n[j] = n;
        }
    }
#pragma unroll
    for (int msk = 1; msk < 16; msk <<= 1) {
#pragma unroll
        for (int j = 0; j < 8; ++j) {
            float om = __shfl_xor(run_m[j], msk, 64);
            float oz = __shfl_xor(run_z[j], msk, 64);
            float on = __shfl_xor(run_n[j], msk, 64);
            float mn = fmaxf(run_m[j], om);
            float s0 = __expf(run_m[j] - mn), s1 = __expf(om - mn);
            run_z[j] = fmaf(run_z[j], s0, oz * s1);
            run_n[j] = fmaf(run_n[j], s0, on * s1);
            run_m[j] = mn;
        }
    }
    if (ty == 0) {
#pragma unroll
        for (int j = 0; j < 8; ++j) {
            int ll = (j < 4) ? (tx * 4 + j) : (64 + tx * 4 + (j - 4));
            size_t idx = ((size_t)(b * L_ + lb + ll) * NC + chunk) * 3;
            part[idx + 0] = run_m[j];
            part[idx + 1] = run_z[j];
            part[idx + 2] = run_n[j];
        }
    }
}

// ---------------- combine partials ----------------
__global__ __launch_bounds__(256) void k_comb(const float* __restrict__ part,
                                              const float* __restrict__ fc_b,
                                              float* __restrict__ out, int nc) {
    int bl = blockIdx.x * 256 + threadIdx.x;
    float m = -1e30f, z = 0.f, n = 0.f;
    for (int c = 0; c < nc; ++c) {
        size_t idx = ((size_t)bl * nc + c) * 3;
        float pm = part[idx + 0], pz = part[idx + 1], pn = part[idx + 2];
        float mn = fmaxf(m, pm);
        float s0 = __expf(m - mn), s1 = __expf(pm - mn);
        z = fmaf(z, s0, pz * s1);
        n = fmaf(n, s0, pn * s1);
        m = mn;
    }
    out[bl] = n / z + fc_b[0];
}

extern "C" void kernel_launch(void* const* d_in, const int* in_sizes, int n_in,
                              void* d_out, int out_size, void* d_ws, size_t ws_size,
                              hipStream_t stream) {
    const float* x    = (const float*)d_in[0];
    const float* q    = (const float*)d_in[1];
    const float* fc_w = (const float*)d_in[2];
    const float* fc_b = (const float*)d_in[3];
    float* out = (float*)d_out;
    float* ws  = (float*)d_ws;

    const size_t Y_F    = (size_t)B_ * T_;
    const size_t PART_F = (size_t)B_ * L_ * NTCH * 3;
    const size_t XT_H   = (size_t)B_ * T_ * D_;
    const size_t QT_H   = (size_t)L_ * D_;
    const size_t need   = (Y_F + PART_F) * 4 + (XT_H + QT_H) * 2;

    if (ws_size >= need) {
        float* y    = ws;
        float* part = ws + Y_F;
        _Float16* xt = (_Float16*)(ws + Y_F + PART_F);
        _Float16* qt = xt + XT_H;
        k_prep<<<B_ * T_ / 16, 256, 0, stream>>>(x, fc_w, xt, y);
        k_cvt <<<(L_ * 64) / 256, 256, 0, stream>>>(q, qt);
        k_mfma<<<4096, 256, 0, stream>>>(xt, qt, y, part);
        k_comb<<<B_ * L_ / 256, 256, 0, stream>>>(part, fc_b, out, NTCH);
    } else {
        float* y    = ws;
        float* part = ws + Y_F;
        k_y   <<<B_ * T_ / 4, 256, 0, stream>>>(x, fc_w, y);
        k_main<<<dim3(L_ / BL, NC, B_), 256, 0, stream>>>(x, q, y, part);
        k_comb<<<B_ * L_ / 256, 256, 0, stream>>>(part, fc_b, out, NC);
    }
}

// Round 4
// 290.643 us; speedup vs baseline: 3.2733x; 1.0374x over previous
//
#include <hip/hip_runtime.h>

#define B_ 16
#define T_ 4096
#define D_ 512
#define L_ 1024
#define NTCH (T_ / 64)                     // 64 t-chunks for fp16-path partials
#define PPLANE ((size_t)B_ * NTCH * L_)    // one partial plane (m / z / n)

typedef _Float16 half8 __attribute__((ext_vector_type(8)));
typedef float float4v __attribute__((ext_vector_type(4)));

// async global->LDS, 16B per lane; LDS dest = uniform base + lane*16
__device__ inline void gl_lds(const void* g, void* l) {
    __builtin_amdgcn_global_load_lds(
        (const __attribute__((address_space(1))) unsigned int*)g,
        (__attribute__((address_space(3))) unsigned int*)l, 16, 0, 0);
}

// ---------------- k_prep: register-path fp32->fp16 fragment-order (+ optional y) ----
// One block per 16-row group. Lane (row=lane&15, gq=lane>>4) loads exactly the
// 32B it emits: x[row][kc*32+gq*8 .. +8]. Wave w handles kc = it*4+w. Per-wave
// 16 rows x 128B contiguous global reads (full line use), contiguous 1KB half8
// stores. y from the same registers; fc_w loads are 16-lane-uniform (broadcast).
__global__ __launch_bounds__(256) void k_prep(const float* __restrict__ src,
                                              const float* __restrict__ w,
                                              _Float16* __restrict__ dst,
                                              float* __restrict__ y, int do_y) {
    __shared__ float Yp[64];
    const int tid  = threadIdx.x;
    const int wv   = tid >> 6;
    const int lane = tid & 63;
    const int row  = lane & 15, gq = lane >> 4;
    const float* bsrc = src + (size_t)blockIdx.x * (16 * 512);
    half8* bdst = (half8*)dst + (size_t)blockIdx.x * 1024;  // 16 kc-blocks x 64 half8

    float acc = 0.f;
#pragma unroll
    for (int it = 0; it < 4; ++it) {
        int kc = it * 4 + wv;
        int k0 = kc * 32 + gq * 8;
        float4 a = *(const float4*)(bsrc + row * 512 + k0);
        float4 c = *(const float4*)(bsrc + row * 512 + k0 + 4);
        half8 h;
        h[0] = (_Float16)a.x; h[1] = (_Float16)a.y; h[2] = (_Float16)a.z; h[3] = (_Float16)a.w;
        h[4] = (_Float16)c.x; h[5] = (_Float16)c.y; h[6] = (_Float16)c.z; h[7] = (_Float16)c.w;
        bdst[kc * 64 + lane] = h;
        if (do_y) {
            float4 wa = *(const float4*)(w + k0);
            float4 wc = *(const float4*)(w + k0 + 4);
            acc = fmaf(a.x, wa.x, acc); acc = fmaf(a.y, wa.y, acc);
            acc = fmaf(a.z, wa.z, acc); acc = fmaf(a.w, wa.w, acc);
            acc = fmaf(c.x, wc.x, acc); acc = fmaf(c.y, wc.y, acc);
            acc = fmaf(c.z, wc.z, acc); acc = fmaf(c.w, wc.w, acc);
        }
    }
    if (do_y) {
        acc += __shfl_xor(acc, 16, 64);
        acc += __shfl_xor(acc, 32, 64);
        if (gq == 0) Yp[wv * 16 + row] = acc;
        __syncthreads();
        if (tid < 16)
            y[blockIdx.x * 16 + tid] = Yp[tid] + Yp[16 + tid] + Yp[32 + tid] + Yp[48 + tid];
    }
}

// ---------------- k_mfma: fused fp16 score-GEMM + online softmax ----------------
// 1-D grid 4096, XCD-swizzled: all 8 l-blocks of a (b,t)-tile on one XCD.
// Partials written plane-major [b][tchunk][L] -> 64B-coalesced quad-0 stores.
__global__ __launch_bounds__(256, 4) void k_mfma(const _Float16* __restrict__ xt,
                                                 const _Float16* __restrict__ qt,
                                                 const float* __restrict__ y,
                                                 float* __restrict__ part) {
    __shared__ half8 S[1024];   // [0,512): x tile, [512,1024): q tile
    __shared__ float ys[128];

    const int bid  = blockIdx.x;
    const int xcd  = bid & 7;
    const int jj   = bid >> 3;
    const int tile = (xcd << 6) | (jj >> 3);   // 512 (b,t) tiles, 64 per XCD
    const int lblk = jj & 7;
    const int tblk = tile & 31;
    const int b    = tile >> 5;

    const int tid  = threadIdx.x;
    const int lane = tid & 63;
    const int w    = tid >> 6;
    const int tb0  = b * (T_ / 16) + tblk * 8;  // 16-row block base (x)
    const int lb0  = lblk * 8;                  // 16-row block base (q)

    if (tid < 128) ys[tid] = y[(size_t)b * T_ + tblk * 128 + tid];

    float4v acc[4][4];
#pragma unroll
    for (int i = 0; i < 4; ++i)
#pragma unroll
        for (int j = 0; j < 4; ++j) acc[i][j] = (float4v){0.f, 0.f, 0.f, 0.f};

    const half8* Xg = (const half8*)xt;
    const half8* Qg = (const half8*)qt;
    const int xa = tb0 + 2 * w;
    const int qa = lb0 + 2 * w;
    const int ts = (w >> 1) * 4, ls = (w & 1) * 4;

    for (int kc = 0; kc < D_ / 32; ++kc) {
        __syncthreads();
        gl_lds(Xg + ((size_t)xa * (D_ / 32) + kc) * 64 + lane,       &S[(2 * w) * 64]);
        gl_lds(Xg + ((size_t)(xa + 1) * (D_ / 32) + kc) * 64 + lane, &S[(2 * w + 1) * 64]);
        gl_lds(Qg + ((size_t)qa * (D_ / 32) + kc) * 64 + lane,       &S[512 + (2 * w) * 64]);
        gl_lds(Qg + ((size_t)(qa + 1) * (D_ / 32) + kc) * 64 + lane, &S[512 + (2 * w + 1) * 64]);
        __syncthreads();

        half8 A[4], Bv[4];
#pragma unroll
        for (int i = 0; i < 4; ++i) A[i] = S[(ts + i) * 64 + lane];
#pragma unroll
        for (int j = 0; j < 4; ++j) Bv[j] = S[512 + (ls + j) * 64 + lane];
#pragma unroll
        for (int i = 0; i < 4; ++i)
#pragma unroll
            for (int j = 0; j < 4; ++j)
                acc[i][j] = __builtin_amdgcn_mfma_f32_16x16x32_f16(A[i], Bv[j], acc[i][j], 0, 0, 0);
    }

    const int quad = lane >> 4, cl = lane & 15;
    const int tw = (w >> 1) * 64;
    const int tchunk = tblk * 2 + (w >> 1);
    const int lbase = lblk * 128 + (w & 1) * 64;

    float* pm = part;
    float* pz = part + PPLANE;
    float* pn = part + 2 * PPLANE;

#pragma unroll
    for (int j = 0; j < 4; ++j) {
        float m = -1e30f;
#pragma unroll
        for (int i = 0; i < 4; ++i)
#pragma unroll
            for (int r = 0; r < 4; ++r) m = fmaxf(m, acc[i][j][r]);
        float z = 0.f, n = 0.f;
#pragma unroll
        for (int i = 0; i < 4; ++i)
#pragma unroll
            for (int r = 0; r < 4; ++r) {
                float p = __expf(acc[i][j][r] - m);
                z += p;
                n = fmaf(p, ys[tw + i * 16 + quad * 4 + r], n);
            }
#pragma unroll
        for (int msk = 16; msk <= 32; msk <<= 1) {
            float om = __shfl_xor(m, msk, 64);
            float oz = __shfl_xor(z, msk, 64);
            float on = __shfl_xor(n, msk, 64);
            float mn = fmaxf(m, om);
            float s0 = __expf(m - mn), s1 = __expf(om - mn);
            z = fmaf(z, s0, oz * s1);
            n = fmaf(n, s0, on * s1);
            m = mn;
        }
        if (quad == 0) {
            int l = lbase + j * 16 + cl;
            size_t a = ((size_t)b * NTCH + tchunk) * L_ + l;  // 16 consecutive floats
            pm[a] = m;
            pz[a] = z;
            pn[a] = n;
        }
    }
}

// ---------------- k_comb_p: combine plane-major partials ----------------
__global__ __launch_bounds__(256) void k_comb_p(const float* __restrict__ part,
                                                const float* __restrict__ fc_b,
                                                float* __restrict__ out) {
    int bl = blockIdx.x * 256 + threadIdx.x;   // b*L + l
    int b = bl >> 10, l = bl & (L_ - 1);
    const float* pm = part;
    const float* pz = part + PPLANE;
    const float* pn = part + 2 * PPLANE;
    float m = -1e30f, z = 0.f, n = 0.f;
    for (int c = 0; c < NTCH; ++c) {
        size_t a = ((size_t)b * NTCH + c) * L_ + l;   // coalesced across wave
        float pmv = pm[a], pzv = pz[a], pnv = pn[a];
        float mn = fmaxf(m, pmv);
        float s0 = __expf(m - mn), s1 = __expf(pmv - mn);
        z = fmaf(z, s0, pzv * s1);
        n = fmaf(n, s0, pnv * s1);
        m = mn;
    }
    out[bl] = n / z + fc_b[0];
}

// ================= fallback fp32 path (round-1) =================
#define NC 8
#define TC (T_ / NC)
#define BT 128
#define BL 128
#define KK 32

__global__ __launch_bounds__(256) void k_y(const float* __restrict__ x,
                                           const float* __restrict__ w,
                                           float* __restrict__ y) {
    int row  = (blockIdx.x * 256 + threadIdx.x) >> 6;
    int lane = threadIdx.x & 63;
    const float* r = x + (size_t)row * D_;
    float s = 0.f;
#pragma unroll
    for (int k = 0; k < D_; k += 64) s = fmaf(r[k + lane], w[k + lane], s);
#pragma unroll
    for (int o = 32; o > 0; o >>= 1) s += __shfl_xor(s, o, 64);
    if (lane == 0) y[row] = s;
}

__global__ __launch_bounds__(256, 2) void k_main(const float* __restrict__ x,
                                                 const float* __restrict__ q,
                                                 const float* __restrict__ y,
                                                 float* __restrict__ part) {
    __shared__ float Xs[KK][BT + 4];
    __shared__ float Qs[KK][BL + 4];
    const int tid = threadIdx.x;
    const int ty = tid & 15, tx = tid >> 4;
    const int lb = blockIdx.x * BL, chunk = blockIdx.y, b = blockIdx.z;
    const int g = tid & 7, r0 = tid >> 3;

    float run_m[8], run_z[8], run_n[8];
#pragma unroll
    for (int j = 0; j < 8; ++j) { run_m[j] = -1e30f; run_z[j] = 0.f; run_n[j] = 0.f; }

    for (int tt = 0; tt < TC; tt += BT) {
        const int t0 = chunk * TC + tt;
        float s[8][8];
#pragma unroll
        for (int i = 0; i < 8; ++i)
#pragma unroll
            for (int j = 0; j < 8; ++j) s[i][j] = 0.f;
        for (int kc = 0; kc < D_; kc += KK) {
            __syncthreads();
#pragma unroll
            for (int p = 0; p < 4; ++p) {
                int rr = p * 32 + r0;
                float4 vx = *(const float4*)(x + ((size_t)b * T_ + t0 + rr) * D_ + kc + g * 4);
                float4 vq = *(const float4*)(q + (size_t)(lb + rr) * D_ + kc + g * 4);
                Xs[g * 4 + 0][rr] = vx.x; Xs[g * 4 + 1][rr] = vx.y;
                Xs[g * 4 + 2][rr] = vx.z; Xs[g * 4 + 3][rr] = vx.w;
                Qs[g * 4 + 0][rr] = vq.x; Qs[g * 4 + 1][rr] = vq.y;
                Qs[g * 4 + 2][rr] = vq.z; Qs[g * 4 + 3][rr] = vq.w;
            }
            __syncthreads();
#pragma unroll
            for (int k = 0; k < KK; ++k) {
                float4 a0 = *(const float4*)&Xs[k][ty * 4];
                float4 a1 = *(const float4*)&Xs[k][64 + ty * 4];
                float4 b0 = *(const float4*)&Qs[k][tx * 4];
                float4 b1 = *(const float4*)&Qs[k][64 + tx * 4];
                float av[8] = {a0.x, a0.y, a0.z, a0.w, a1.x, a1.y, a1.z, a1.w};
                float bv[8] = {b0.x, b0.y, b0.z, b0.w, b1.x, b1.y, b1.z, b1.w};
#pragma unroll
                for (int i = 0; i < 8; ++i)
#pragma unroll
                    for (int j = 0; j < 8; ++j) s[i][j] = fmaf(av[i], bv[j], s[i][j]);
            }
        }
        float yv[8];
#pragma unroll
        for (int i = 0; i < 8; ++i) {
            int tl = (i < 4) ? (ty * 4 + i) : (64 + ty * 4 + (i - 4));
            yv[i] = y[(size_t)b * T_ + t0 + tl];
        }
#pragma unroll
        for (int j = 0; j < 8; ++j) {
            float mt = s[0][j];
#pragma unroll
            for (int i = 1; i < 8; ++i) mt = fmaxf(mt, s[i][j]);
            float mn = fmaxf(run_m[j], mt);
            float sc = __expf(run_m[j] - mn);
            float z = run_z[j] * sc, n = run_n[j] * sc;
#pragma unroll
            for (int i = 0; i < 8; ++i) {
                float p = __expf(s[i][j] - mn);
                z += p;
                n = fmaf(p, yv[i], n);
            }
            run_m[j] = mn; run_z[j] = z; run_n[j] = n;
        }
    }
#pragma unroll
    for (int msk = 1; msk < 16; msk <<= 1) {
#pragma unroll
        for (int j = 0; j < 8; ++j) {
            float om = __shfl_xor(run_m[j], msk, 64);
            float oz = __shfl_xor(run_z[j], msk, 64);
            float on = __shfl_xor(run_n[j], msk, 64);
            float mn = fmaxf(run_m[j], om);
            float s0 = __expf(run_m[j] - mn), s1 = __expf(om - mn);
            run_z[j] = fmaf(run_z[j], s0, oz * s1);
            run_n[j] = fmaf(run_n[j], s0, on * s1);
            run_m[j] = mn;
        }
    }
    if (ty == 0) {
#pragma unroll
        for (int j = 0; j < 8; ++j) {
            int ll = (j < 4) ? (tx * 4 + j) : (64 + tx * 4 + (j - 4));
            size_t idx = ((size_t)(b * L_ + lb + ll) * NC + chunk) * 3;
            part[idx + 0] = run_m[j];
            part[idx + 1] = run_z[j];
            part[idx + 2] = run_n[j];
        }
    }
}

__global__ __launch_bounds__(256) void k_comb_f(const float* __restrict__ part,
                                                const float* __restrict__ fc_b,
                                                float* __restrict__ out) {
    int bl = blockIdx.x * 256 + threadIdx.x;
    float m = -1e30f, z = 0.f, n = 0.f;
    for (int c = 0; c < NC; ++c) {
        size_t idx = ((size_t)bl * NC + c) * 3;
        float pm = part[idx + 0], pz = part[idx + 1], pn = part[idx + 2];
        float mn = fmaxf(m, pm);
        float s0 = __expf(m - mn), s1 = __expf(pm - mn);
        z = fmaf(z, s0, pz * s1);
        n = fmaf(n, s0, pn * s1);
        m = mn;
    }
    out[bl] = n / z + fc_b[0];
}

extern "C" void kernel_launch(void* const* d_in, const int* in_sizes, int n_in,
                              void* d_out, int out_size, void* d_ws, size_t ws_size,
                              hipStream_t stream) {
    const float* x    = (const float*)d_in[0];
    const float* q    = (const float*)d_in[1];
    const float* fc_w = (const float*)d_in[2];
    const float* fc_b = (const float*)d_in[3];
    float* out = (float*)d_out;
    float* ws  = (float*)d_ws;

    const size_t Y_F    = (size_t)B_ * T_;
    const size_t PART_F = 3 * PPLANE;
    const size_t XT_H   = (size_t)B_ * T_ * D_;
    const size_t QT_H   = (size_t)L_ * D_;
    const size_t need   = (Y_F + PART_F) * 4 + (XT_H + QT_H) * 2;

    if (ws_size >= need) {
        float* y    = ws;
        float* part = ws + Y_F;
        _Float16* xt = (_Float16*)(ws + Y_F + PART_F);
        _Float16* qt = xt + XT_H;
        k_prep<<<B_ * T_ / 16, 256, 0, stream>>>(x, fc_w, xt, y, 1);
        k_prep<<<L_ / 16, 256, 0, stream>>>(q, fc_w, qt, nullptr, 0);
        k_mfma<<<4096, 256, 0, stream>>>(xt, qt, y, part);
        k_comb_p<<<B_ * L_ / 256, 256, 0, stream>>>(part, fc_b, out);
    } else {
        float* y    = ws;
        float* part = ws + Y_F;
        k_y   <<<B_ * T_ / 4, 256, 0, stream>>>(x, fc_w, y);
        k_main<<<dim3(L_ / BL, NC, B_), 256, 0, stream>>>(x, q, y, part);
        k_comb_f<<<B_ * L_ / 256, 256, 0, stream>>>(part, fc_b, out);
    }
}

// Round 5
// 282.038 us; speedup vs baseline: 3.3732x; 1.0305x over previous
//
#include <hip/hip_runtime.h>

#define B_ 16
#define T_ 4096
#define D_ 512
#define L_ 1024
#define NTCH (T_ / 64)                     // 64 t-chunks for fp16-path partials
#define PPLANE ((size_t)B_ * NTCH * L_)    // one partial plane (m / z / n)
#define XBLK (B_ * T_ / 16)                // 4096 x prep blocks

typedef _Float16 half8 __attribute__((ext_vector_type(8)));
typedef float float4v __attribute__((ext_vector_type(4)));

// async global->LDS, 16B per lane; LDS dest = uniform base + lane*16
__device__ inline void gl_lds(const void* g, void* l) {
    __builtin_amdgcn_global_load_lds(
        (const __attribute__((address_space(1))) unsigned int*)g,
        (__attribute__((address_space(3))) unsigned int*)l, 16, 0, 0);
}

// ---------------- k_prep v3: coalesced load -> LDS transpose -> fragment-order fp16 ----
// One block per 16-row group (x blocks: [0,4096), q blocks: [4096,4160)).
// Phase 1: fully-coalesced float4 global reads into LDS, row stride 516 floats
// (2064B, 16B-aligned; phase-level bank aliasing 2-way = free).
// Phase 2: fragment-order ds_read_b128 gather, convert, contiguous 1KB stores.
// y computed from the same registers (fc_w loads are 16-lane-uniform).
__global__ __launch_bounds__(256) void k_prep(const float* __restrict__ x,
                                              const float* __restrict__ q,
                                              const float* __restrict__ w,
                                              _Float16* __restrict__ xt,
                                              _Float16* __restrict__ qt,
                                              float* __restrict__ y) {
    __shared__ float Xl[16 * 516];
    __shared__ float Yp[64];
    const int tid = threadIdx.x;
    const bool isq = blockIdx.x >= XBLK;
    const int blk = isq ? (blockIdx.x - XBLK) : blockIdx.x;
    const float* bsrc = (isq ? q : x) + (size_t)blk * (16 * 512);
    half8* dst = (half8*)(isq ? qt : xt) + (size_t)blk * 1024;

#pragma unroll
    for (int it = 0; it < 8; ++it) {
        int f = it * 1024 + tid * 4;       // contiguous 4KB per wave-instr
        int row = f >> 9, k = f & 511;
        *(float4*)&Xl[row * 516 + k] = *(const float4*)(bsrc + f);
    }
    __syncthreads();

    const int wv = tid >> 6, lane = tid & 63;
    const int row = lane & 15, gq = lane >> 4;
    float acc = 0.f;
#pragma unroll
    for (int it = 0; it < 4; ++it) {
        int kc = it * 4 + wv;
        int k0 = kc * 32 + gq * 8;
        float4 a = *(const float4*)&Xl[row * 516 + k0];
        float4 c = *(const float4*)&Xl[row * 516 + k0 + 4];
        half8 h;
        h[0] = (_Float16)a.x; h[1] = (_Float16)a.y; h[2] = (_Float16)a.z; h[3] = (_Float16)a.w;
        h[4] = (_Float16)c.x; h[5] = (_Float16)c.y; h[6] = (_Float16)c.z; h[7] = (_Float16)c.w;
        dst[kc * 64 + lane] = h;
        if (!isq) {
            float4 wa = *(const float4*)(w + k0);
            float4 wc = *(const float4*)(w + k0 + 4);
            acc = fmaf(a.x, wa.x, acc); acc = fmaf(a.y, wa.y, acc);
            acc = fmaf(a.z, wa.z, acc); acc = fmaf(a.w, wa.w, acc);
            acc = fmaf(c.x, wc.x, acc); acc = fmaf(c.y, wc.y, acc);
            acc = fmaf(c.z, wc.z, acc); acc = fmaf(c.w, wc.w, acc);
        }
    }
    if (!isq) {
        acc += __shfl_xor(acc, 16, 64);
        acc += __shfl_xor(acc, 32, 64);
        if (gq == 0) Yp[wv * 16 + row] = acc;
        __syncthreads();
        if (tid < 16)
            y[blk * 16 + tid] = Yp[tid] + Yp[16 + tid] + Yp[32 + tid] + Yp[48 + tid];
    }
}

// ---------------- k_mfma: fused fp16 score-GEMM + online softmax (BK=64) ----------------
// 1-D grid 4096, XCD-swizzled. 2 k-chunks staged per barrier pair: 8 iters,
// 32 MFMA per wave per barrier. Partials plane-major [b][tchunk][L].
__global__ __launch_bounds__(256, 4) void k_mfma(const _Float16* __restrict__ xt,
                                                 const _Float16* __restrict__ qt,
                                                 const float* __restrict__ y,
                                                 float* __restrict__ part) {
    __shared__ half8 S[2048];   // [0,1024): x (2 kc x 8 blk), [1024,2048): q
    __shared__ float ys[128];

    const int bid  = blockIdx.x;
    const int xcd  = bid & 7;
    const int jj   = bid >> 3;
    const int tile = (xcd << 6) | (jj >> 3);   // 512 (b,t) tiles, 64 per XCD
    const int lblk = jj & 7;
    const int tblk = tile & 31;
    const int b    = tile >> 5;

    const int tid  = threadIdx.x;
    const int lane = tid & 63;
    const int w    = tid >> 6;
    const int tb0  = b * (T_ / 16) + tblk * 8;
    const int lb0  = lblk * 8;

    if (tid < 128) ys[tid] = y[(size_t)b * T_ + tblk * 128 + tid];

    float4v acc[4][4];
#pragma unroll
    for (int i = 0; i < 4; ++i)
#pragma unroll
        for (int j = 0; j < 4; ++j) acc[i][j] = (float4v){0.f, 0.f, 0.f, 0.f};

    const half8* Xg = (const half8*)xt;
    const half8* Qg = (const half8*)qt;
    const int xa = tb0 + 2 * w;
    const int qa = lb0 + 2 * w;
    const int ts = (w >> 1) * 4, ls = (w & 1) * 4;

    for (int kk = 0; kk < D_ / 64; ++kk) {
        const int kc0 = kk * 2;
        __syncthreads();
#pragma unroll
        for (int s = 0; s < 2; ++s) {
            gl_lds(Xg + ((size_t)xa * (D_ / 32) + kc0 + s) * 64 + lane,
                   &S[s * 512 + (2 * w) * 64]);
            gl_lds(Xg + ((size_t)(xa + 1) * (D_ / 32) + kc0 + s) * 64 + lane,
                   &S[s * 512 + (2 * w + 1) * 64]);
            gl_lds(Qg + ((size_t)qa * (D_ / 32) + kc0 + s) * 64 + lane,
                   &S[1024 + s * 512 + (2 * w) * 64]);
            gl_lds(Qg + ((size_t)(qa + 1) * (D_ / 32) + kc0 + s) * 64 + lane,
                   &S[1024 + s * 512 + (2 * w + 1) * 64]);
        }
        __syncthreads();

#pragma unroll
        for (int s = 0; s < 2; ++s) {
            half8 A[4], Bv[4];
#pragma unroll
            for (int i = 0; i < 4; ++i) A[i] = S[s * 512 + (ts + i) * 64 + lane];
#pragma unroll
            for (int j = 0; j < 4; ++j) Bv[j] = S[1024 + s * 512 + (ls + j) * 64 + lane];
#pragma unroll
            for (int i = 0; i < 4; ++i)
#pragma unroll
                for (int j = 0; j < 4; ++j)
                    acc[i][j] = __builtin_amdgcn_mfma_f32_16x16x32_f16(A[i], Bv[j], acc[i][j], 0, 0, 0);
        }
    }

    const int quad = lane >> 4, cl = lane & 15;
    const int tw = (w >> 1) * 64;
    const int tchunk = tblk * 2 + (w >> 1);
    const int lbase = lblk * 128 + (w & 1) * 64;

    float* pm = part;
    float* pz = part + PPLANE;
    float* pn = part + 2 * PPLANE;

#pragma unroll
    for (int j = 0; j < 4; ++j) {
        float m = -1e30f;
#pragma unroll
        for (int i = 0; i < 4; ++i)
#pragma unroll
            for (int r = 0; r < 4; ++r) m = fmaxf(m, acc[i][j][r]);
        float z = 0.f, n = 0.f;
#pragma unroll
        for (int i = 0; i < 4; ++i)
#pragma unroll
            for (int r = 0; r < 4; ++r) {
                float p = __expf(acc[i][j][r] - m);
                z += p;
                n = fmaf(p, ys[tw + i * 16 + quad * 4 + r], n);
            }
#pragma unroll
        for (int msk = 16; msk <= 32; msk <<= 1) {
            float om = __shfl_xor(m, msk, 64);
            float oz = __shfl_xor(z, msk, 64);
            float on = __shfl_xor(n, msk, 64);
            float mn = fmaxf(m, om);
            float s0 = __expf(m - mn), s1 = __expf(om - mn);
            z = fmaf(z, s0, oz * s1);
            n = fmaf(n, s0, on * s1);
            m = mn;
        }
        if (quad == 0) {
            int l = lbase + j * 16 + cl;
            size_t a = ((size_t)b * NTCH + tchunk) * L_ + l;
            pm[a] = m;
            pz[a] = z;
            pn[a] = n;
        }
    }
}

// ---------------- k_comb_p: combine plane-major partials ----------------
__global__ __launch_bounds__(256) void k_comb_p(const float* __restrict__ part,
                                                const float* __restrict__ fc_b,
                                                float* __restrict__ out) {
    int bl = blockIdx.x * 256 + threadIdx.x;
    int b = bl >> 10, l = bl & (L_ - 1);
    const float* pm = part;
    const float* pz = part + PPLANE;
    const float* pn = part + 2 * PPLANE;
    float m = -1e30f, z = 0.f, n = 0.f;
    for (int c = 0; c < NTCH; ++c) {
        size_t a = ((size_t)b * NTCH + c) * L_ + l;
        float pmv = pm[a], pzv = pz[a], pnv = pn[a];
        float mn = fmaxf(m, pmv);
        float s0 = __expf(m - mn), s1 = __expf(pmv - mn);
        z = fmaf(z, s0, pzv * s1);
        n = fmaf(n, s0, pnv * s1);
        m = mn;
    }
    out[bl] = n / z + fc_b[0];
}

// ================= fallback fp32 path (round-1) =================
#define NC 8
#define TC (T_ / NC)
#define BT 128
#define BL 128
#define KK 32

__global__ __launch_bounds__(256) void k_y(const float* __restrict__ x,
                                           const float* __restrict__ w,
                                           float* __restrict__ y) {
    int row  = (blockIdx.x * 256 + threadIdx.x) >> 6;
    int lane = threadIdx.x & 63;
    const float* r = x + (size_t)row * D_;
    float s = 0.f;
#pragma unroll
    for (int k = 0; k < D_; k += 64) s = fmaf(r[k + lane], w[k + lane], s);
#pragma unroll
    for (int o = 32; o > 0; o >>= 1) s += __shfl_xor(s, o, 64);
    if (lane == 0) y[row] = s;
}

__global__ __launch_bounds__(256, 2) void k_main(const float* __restrict__ x,
                                                 const float* __restrict__ q,
                                                 const float* __restrict__ y,
                                                 float* __restrict__ part) {
    __shared__ float Xs[KK][BT + 4];
    __shared__ float Qs[KK][BL + 4];
    const int tid = threadIdx.x;
    const int ty = tid & 15, tx = tid >> 4;
    const int lb = blockIdx.x * BL, chunk = blockIdx.y, b = blockIdx.z;
    const int g = tid & 7, r0 = tid >> 3;

    float run_m[8], run_z[8], run_n[8];
#pragma unroll
    for (int j = 0; j < 8; ++j) { run_m[j] = -1e30f; run_z[j] = 0.f; run_n[j] = 0.f; }

    for (int tt = 0; tt < TC; tt += BT) {
        const int t0 = chunk * TC + tt;
        float s[8][8];
#pragma unroll
        for (int i = 0; i < 8; ++i)
#pragma unroll
            for (int j = 0; j < 8; ++j) s[i][j] = 0.f;
        for (int kc = 0; kc < D_; kc += KK) {
            __syncthreads();
#pragma unroll
            for (int p = 0; p < 4; ++p) {
                int rr = p * 32 + r0;
                float4 vx = *(const float4*)(x + ((size_t)b * T_ + t0 + rr) * D_ + kc + g * 4);
                float4 vq = *(const float4*)(q + (size_t)(lb + rr) * D_ + kc + g * 4);
                Xs[g * 4 + 0][rr] = vx.x; Xs[g * 4 + 1][rr] = vx.y;
                Xs[g * 4 + 2][rr] = vx.z; Xs[g * 4 + 3][rr] = vx.w;
                Qs[g * 4 + 0][rr] = vq.x; Qs[g * 4 + 1][rr] = vq.y;
                Qs[g * 4 + 2][rr] = vq.z; Qs[g * 4 + 3][rr] = vq.w;
            }
            __syncthreads();
#pragma unroll
            for (int k = 0; k < KK; ++k) {
                float4 a0 = *(const float4*)&Xs[k][ty * 4];
                float4 a1 = *(const float4*)&Xs[k][64 + ty * 4];
                float4 b0 = *(const float4*)&Qs[k][tx * 4];
                float4 b1 = *(const float4*)&Qs[k][64 + tx * 4];
                float av[8] = {a0.x, a0.y, a0.z, a0.w, a1.x, a1.y, a1.z, a1.w};
                float bv[8] = {b0.x, b0.y, b0.z, b0.w, b1.x, b1.y, b1.z, b1.w};
#pragma unroll
                for (int i = 0; i < 8; ++i)
#pragma unroll
                    for (int j = 0; j < 8; ++j) s[i][j] = fmaf(av[i], bv[j], s[i][j]);
            }
        }
        float yv[8];
#pragma unroll
        for (int i = 0; i < 8; ++i) {
            int tl = (i < 4) ? (ty * 4 + i) : (64 + ty * 4 + (i - 4));
            yv[i] = y[(size_t)b * T_ + t0 + tl];
        }
#pragma unroll
        for (int j = 0; j < 8; ++j) {
            float mt = s[0][j];
#pragma unroll
            for (int i = 1; i < 8; ++i) mt = fmaxf(mt, s[i][j]);
            float mn = fmaxf(run_m[j], mt);
            float sc = __expf(run_m[j] - mn);
            float z = run_z[j] * sc, n = run_n[j] * sc;
#pragma unroll
            for (int i = 0; i < 8; ++i) {
                float p = __expf(s[i][j] - mn);
                z += p;
                n = fmaf(p, yv[i], n);
            }
            run_m[j] = mn; run_z[j] = z; run_n[j] = n;
        }
    }
#pragma unroll
    for (int msk = 1; msk < 16; msk <<= 1) {
#pragma unroll
        for (int j = 0; j < 8; ++j) {
            float om = __shfl_xor(run_m[j], msk, 64);
            float oz = __shfl_xor(run_z[j], msk, 64);
            float on = __shfl_xor(run_n[j], msk, 64);
            float mn = fmaxf(run_m[j], om);
            float s0 = __expf(run_m[j] - mn), s1 = __expf(om - mn);
            run_z[j] = fmaf(run_z[j], s0, oz * s1);
            run_n[j] = fmaf(run_n[j], s0, on * s1);
            run_m[j] = mn;
        }
    }
    if (ty == 0) {
#pragma unroll
        for (int j = 0; j < 8; ++j) {
            int ll = (j < 4) ? (tx * 4 + j) : (64 + tx * 4 + (j - 4));
            size_t idx = ((size_t)(b * L_ + lb + ll) * NC + chunk) * 3;
            part[idx + 0] = run_m[j];
            part[idx + 1] = run_z[j];
            part[idx + 2] = run_n[j];
        }
    }
}

__global__ __launch_bounds__(256) void k_comb_f(const float* __restrict__ part,
                                                const float* __restrict__ fc_b,
                                                float* __restrict__ out) {
    int bl = blockIdx.x * 256 + threadIdx.x;
    float m = -1e30f, z = 0.f, n = 0.f;
    for (int c = 0; c < NC; ++c) {
        size_t idx = ((size_t)bl * NC + c) * 3;
        float pm = part[idx + 0], pz = part[idx + 1], pn = part[idx + 2];
        float mn = fmaxf(m, pm);
        float s0 = __expf(m - mn), s1 = __expf(pm - mn);
        z = fmaf(z, s0, pz * s1);
        n = fmaf(n, s0, pn * s1);
        m = mn;
    }
    out[bl] = n / z + fc_b[0];
}

extern "C" void kernel_launch(void* const* d_in, const int* in_sizes, int n_in,
                              void* d_out, int out_size, void* d_ws, size_t ws_size,
                              hipStream_t stream) {
    const float* x    = (const float*)d_in[0];
    const float* q    = (const float*)d_in[1];
    const float* fc_w = (const float*)d_in[2];
    const float* fc_b = (const float*)d_in[3];
    float* out = (float*)d_out;
    float* ws  = (float*)d_ws;

    const size_t Y_F    = (size_t)B_ * T_;
    const size_t PART_F = 3 * PPLANE;
    const size_t XT_H   = (size_t)B_ * T_ * D_;
    const size_t QT_H   = (size_t)L_ * D_;
    const size_t need   = (Y_F + PART_F) * 4 + (XT_H + QT_H) * 2;

    if (ws_size >= need) {
        float* y    = ws;
        float* part = ws + Y_F;
        _Float16* xt = (_Float16*)(ws + Y_F + PART_F);
        _Float16* qt = xt + XT_H;
        k_prep<<<XBLK + L_ / 16, 256, 0, stream>>>(x, q, fc_w, xt, qt, y);
        k_mfma<<<4096, 256, 0, stream>>>(xt, qt, y, part);
        k_comb_p<<<B_ * L_ / 256, 256, 0, stream>>>(part, fc_b, out);
    } else {
        float* y    = ws;
        float* part = ws + Y_F;
        k_y   <<<B_ * T_ / 4, 256, 0, stream>>>(x, fc_w, y);
        k_main<<<dim3(L_ / BL, NC, B_), 256, 0, stream>>>(x, q, y, part);
        k_comb_f<<<B_ * L_ / 256, 256, 0, stream>>>(part, fc_b, out);
    }
}

// Round 6
// 277.447 us; speedup vs baseline: 3.4290x; 1.0165x over previous
//
#include <hip/hip_runtime.h>

#define B_ 16
#define T_ 4096
#define D_ 512
#define L_ 1024
#define NTCH 32                            // 128-t chunks for fp16-path partials
#define PPLANE ((size_t)B_ * NTCH * L_)    // one partial plane (m / z / n)
#define XBLK (B_ * T_ / 16)                // 4096 x prep blocks

typedef _Float16 half8 __attribute__((ext_vector_type(8)));
typedef float float4v __attribute__((ext_vector_type(4)));

// async global->LDS, 16B per lane; LDS dest = uniform base + lane*16
__device__ inline void gl_lds(const void* g, void* l) {
    __builtin_amdgcn_global_load_lds(
        (const __attribute__((address_space(1))) unsigned int*)g,
        (__attribute__((address_space(3))) unsigned int*)l, 16, 0, 0);
}

// ---------------- k_prep v4: coalesced load -> XOR-swizzled LDS -> fragment fp16 ----
// One block per 16-row group (x: [0,4096), q: [4096,4160)).
// LDS layout: float4 at logical (row, 16B-chunk c) stored at chunk c^(row&7).
// Both phases then cover complete 256B bank rows per quarter-wave (2-way, free).
__global__ __launch_bounds__(256) void k_prep(const float* __restrict__ x,
                                              const float* __restrict__ q,
                                              const float* __restrict__ w,
                                              _Float16* __restrict__ xt,
                                              _Float16* __restrict__ qt,
                                              float* __restrict__ y) {
    __shared__ float Xl[16 * 512];
    __shared__ float Yp[64];
    const int tid = threadIdx.x;
    const bool isq = blockIdx.x >= XBLK;
    const int blk = isq ? (blockIdx.x - XBLK) : blockIdx.x;
    const float* bsrc = (isq ? q : x) + (size_t)blk * (16 * 512);
    half8* dst = (half8*)(isq ? qt : xt) + (size_t)blk * 1024;

#pragma unroll
    for (int it = 0; it < 8; ++it) {
        int f = it * 1024 + tid * 4;       // contiguous 4KB per wave-instr
        int row = f >> 9, k = f & 511;
        int pc = (k >> 2) ^ (row & 7);     // XOR bank swizzle (16B granules)
        *(float4*)&Xl[row * 512 + pc * 4] = *(const float4*)(bsrc + f);
    }
    __syncthreads();

    const int wv = tid >> 6, lane = tid & 63;
    const int row = lane & 15, gq = lane >> 4;
    float acc = 0.f;
#pragma unroll
    for (int it = 0; it < 4; ++it) {
        int kc = it * 4 + wv;
        int c0 = kc * 8 + gq * 2;          // logical 16B-chunk of this fragment
        int k0 = kc * 32 + gq * 8;         // logical k (for fc_w)
        float4 a = *(const float4*)&Xl[row * 512 + ((c0 ^ (row & 7)) << 2)];
        float4 c = *(const float4*)&Xl[row * 512 + (((c0 + 1) ^ (row & 7)) << 2)];
        half8 h;
        h[0] = (_Float16)a.x; h[1] = (_Float16)a.y; h[2] = (_Float16)a.z; h[3] = (_Float16)a.w;
        h[4] = (_Float16)c.x; h[5] = (_Float16)c.y; h[6] = (_Float16)c.z; h[7] = (_Float16)c.w;
        dst[kc * 64 + lane] = h;           // contiguous 1KB per wave
        if (!isq) {
            float4 wa = *(const float4*)(w + k0);
            float4 wc = *(const float4*)(w + k0 + 4);
            acc = fmaf(a.x, wa.x, acc); acc = fmaf(a.y, wa.y, acc);
            acc = fmaf(a.z, wa.z, acc); acc = fmaf(a.w, wa.w, acc);
            acc = fmaf(c.x, wc.x, acc); acc = fmaf(c.y, wc.y, acc);
            acc = fmaf(c.z, wc.z, acc); acc = fmaf(c.w, wc.w, acc);
        }
    }
    if (!isq) {
        acc += __shfl_xor(acc, 16, 64);
        acc += __shfl_xor(acc, 32, 64);
        if (gq == 0) Yp[wv * 16 + row] = acc;
        __syncthreads();
        if (tid < 16)
            y[blk * 16 + tid] = Yp[tid] + Yp[16 + tid] + Yp[32 + tid] + Yp[48 + tid];
    }
}

// ---------------- k_mfma: block 256t x 128l, wave 128t x 64l, BK=64 ----------------
// 1-D grid 2048, XCD-swizzled (8 l-blocks of a (b,t)-tile on one XCD).
// Wave tile 128x64 halves LDS fragment bytes/FLOP vs 64x64.
__global__ __launch_bounds__(256, 2) void k_mfma(const _Float16* __restrict__ xt,
                                                 const _Float16* __restrict__ qt,
                                                 const float* __restrict__ y,
                                                 float* __restrict__ part) {
    __shared__ half8 S[3072];   // per s(2): [0,1024) x (16 blks), [1024,1536) q (8 blks)
    __shared__ float ys[256];

    const int bid  = blockIdx.x;
    const int xcd  = bid & 7;
    const int jj   = bid >> 3;
    const int tile = (xcd << 5) | (jj >> 3);   // 256 (b,t256) tiles, 32 per XCD
    const int lblk = jj & 7;
    const int tblk = tile & 15;
    const int b    = tile >> 4;

    const int tid  = threadIdx.x;
    const int lane = tid & 63;
    const int w    = tid >> 6;
    const int wt   = w >> 1, wl = w & 1;
    const int tb0  = b * (T_ / 16) + tblk * 16;  // 16-row block base (x)
    const int lb0  = lblk * 8;                   // 16-row block base (q)

    ys[tid] = y[(size_t)b * T_ + tblk * 256 + tid];

    float4v acc[8][4];
#pragma unroll
    for (int i = 0; i < 8; ++i)
#pragma unroll
        for (int j = 0; j < 4; ++j) acc[i][j] = (float4v){0.f, 0.f, 0.f, 0.f};

    const half8* Xg = (const half8*)xt;
    const half8* Qg = (const half8*)qt;

    for (int kk = 0; kk < D_ / 64; ++kk) {
        __syncthreads();
#pragma unroll
        for (int s = 0; s < 2; ++s) {
            const int kc = kk * 2 + s;
#pragma unroll
            for (int p = 0; p < 4; ++p) {
                int xb = p * 4 + w;
                gl_lds(Xg + ((size_t)(tb0 + xb) * (D_ / 32) + kc) * 64 + lane,
                       &S[s * 1536 + xb * 64]);
            }
#pragma unroll
            for (int p = 0; p < 2; ++p) {
                int qb = p * 4 + w;
                gl_lds(Qg + ((size_t)(lb0 + qb) * (D_ / 32) + kc) * 64 + lane,
                       &S[s * 1536 + 1024 + qb * 64]);
            }
        }
        __syncthreads();

#pragma unroll
        for (int s = 0; s < 2; ++s) {
            half8 A[8], Bv[4];
#pragma unroll
            for (int i = 0; i < 8; ++i) A[i] = S[s * 1536 + (wt * 8 + i) * 64 + lane];
#pragma unroll
            for (int j = 0; j < 4; ++j) Bv[j] = S[s * 1536 + 1024 + (wl * 4 + j) * 64 + lane];
#pragma unroll
            for (int i = 0; i < 8; ++i)
#pragma unroll
                for (int j = 0; j < 4; ++j)
                    acc[i][j] = __builtin_amdgcn_mfma_f32_16x16x32_f16(A[i], Bv[j], acc[i][j], 0, 0, 0);
        }
    }

    const int quad = lane >> 4, cl = lane & 15;
    const int tchunk = tblk * 2 + wt;            // 128-t chunk id
    const int lbase  = lblk * 128 + wl * 64;

    float* pm = part;
    float* pz = part + PPLANE;
    float* pn = part + 2 * PPLANE;

#pragma unroll
    for (int j = 0; j < 4; ++j) {
        float m = -1e30f;
#pragma unroll
        for (int i = 0; i < 8; ++i)
#pragma unroll
            for (int r = 0; r < 4; ++r) m = fmaxf(m, acc[i][j][r]);
        float z = 0.f, n = 0.f;
#pragma unroll
        for (int i = 0; i < 8; ++i)
#pragma unroll
            for (int r = 0; r < 4; ++r) {
                float p = __expf(acc[i][j][r] - m);
                z += p;
                n = fmaf(p, ys[wt * 128 + i * 16 + quad * 4 + r], n);
            }
#pragma unroll
        for (int msk = 16; msk <= 32; msk <<= 1) {
            float om = __shfl_xor(m, msk, 64);
            float oz = __shfl_xor(z, msk, 64);
            float on = __shfl_xor(n, msk, 64);
            float mn = fmaxf(m, om);
            float s0 = __expf(m - mn), s1 = __expf(om - mn);
            z = fmaf(z, s0, oz * s1);
            n = fmaf(n, s0, on * s1);
            m = mn;
        }
        if (quad == 0) {
            int l = lbase + j * 16 + cl;
            size_t a = ((size_t)b * NTCH + tchunk) * L_ + l;   // 16 consecutive floats
            pm[a] = m;
            pz[a] = z;
            pn[a] = n;
        }
    }
}

// ---------------- k_comb_p: combine plane-major partials ----------------
__global__ __launch_bounds__(256) void k_comb_p(const float* __restrict__ part,
                                                const float* __restrict__ fc_b,
                                                float* __restrict__ out) {
    int bl = blockIdx.x * 256 + threadIdx.x;
    int b = bl >> 10, l = bl & (L_ - 1);
    const float* pm = part;
    const float* pz = part + PPLANE;
    const float* pn = part + 2 * PPLANE;
    float m = -1e30f, z = 0.f, n = 0.f;
    for (int c = 0; c < NTCH; ++c) {
        size_t a = ((size_t)b * NTCH + c) * L_ + l;
        float pmv = pm[a], pzv = pz[a], pnv = pn[a];
        float mn = fmaxf(m, pmv);
        float s0 = __expf(m - mn), s1 = __expf(pmv - mn);
        z = fmaf(z, s0, pzv * s1);
        n = fmaf(n, s0, pnv * s1);
        m = mn;
    }
    out[bl] = n / z + fc_b[0];
}

// ================= fallback fp32 path (round-1) =================
#define NC 8
#define TC (T_ / NC)
#define BT 128
#define BL 128
#define KK 32

__global__ __launch_bounds__(256) void k_y(const float* __restrict__ x,
                                           const float* __restrict__ w,
                                           float* __restrict__ y) {
    int row  = (blockIdx.x * 256 + threadIdx.x) >> 6;
    int lane = threadIdx.x & 63;
    const float* r = x + (size_t)row * D_;
    float s = 0.f;
#pragma unroll
    for (int k = 0; k < D_; k += 64) s = fmaf(r[k + lane], w[k + lane], s);
#pragma unroll
    for (int o = 32; o > 0; o >>= 1) s += __shfl_xor(s, o, 64);
    if (lane == 0) y[row] = s;
}

__global__ __launch_bounds__(256, 2) void k_main(const float* __restrict__ x,
                                                 const float* __restrict__ q,
                                                 const float* __restrict__ y,
                                                 float* __restrict__ part) {
    __shared__ float Xs[KK][BT + 4];
    __shared__ float Qs[KK][BL + 4];
    const int tid = threadIdx.x;
    const int ty = tid & 15, tx = tid >> 4;
    const int lb = blockIdx.x * BL, chunk = blockIdx.y, b = blockIdx.z;
    const int g = tid & 7, r0 = tid >> 3;

    float run_m[8], run_z[8], run_n[8];
#pragma unroll
    for (int j = 0; j < 8; ++j) { run_m[j] = -1e30f; run_z[j] = 0.f; run_n[j] = 0.f; }

    for (int tt = 0; tt < TC; tt += BT) {
        const int t0 = chunk * TC + tt;
        float s[8][8];
#pragma unroll
        for (int i = 0; i < 8; ++i)
#pragma unroll
            for (int j = 0; j < 8; ++j) s[i][j] = 0.f;
        for (int kc = 0; kc < D_; kc += KK) {
            __syncthreads();
#pragma unroll
            for (int p = 0; p < 4; ++p) {
                int rr = p * 32 + r0;
                float4 vx = *(const float4*)(x + ((size_t)b * T_ + t0 + rr) * D_ + kc + g * 4);
                float4 vq = *(const float4*)(q + (size_t)(lb + rr) * D_ + kc + g * 4);
                Xs[g * 4 + 0][rr] = vx.x; Xs[g * 4 + 1][rr] = vx.y;
                Xs[g * 4 + 2][rr] = vx.z; Xs[g * 4 + 3][rr] = vx.w;
                Qs[g * 4 + 0][rr] = vq.x; Qs[g * 4 + 1][rr] = vq.y;
                Qs[g * 4 + 2][rr] = vq.z; Qs[g * 4 + 3][rr] = vq.w;
            }
            __syncthreads();
#pragma unroll
            for (int k = 0; k < KK; ++k) {
                float4 a0 = *(const float4*)&Xs[k][ty * 4];
                float4 a1 = *(const float4*)&Xs[k][64 + ty * 4];
                float4 b0 = *(const float4*)&Qs[k][tx * 4];
                float4 b1 = *(const float4*)&Qs[k][64 + tx * 4];
                float av[8] = {a0.x, a0.y, a0.z, a0.w, a1.x, a1.y, a1.z, a1.w};
                float bv[8] = {b0.x, b0.y, b0.z, b0.w, b1.x, b1.y, b1.z, b1.w};
#pragma unroll
                for (int i = 0; i < 8; ++i)
#pragma unroll
                    for (int j = 0; j < 8; ++j) s[i][j] = fmaf(av[i], bv[j], s[i][j]);
            }
        }
        float yv[8];
#pragma unroll
        for (int i = 0; i < 8; ++i) {
            int tl = (i < 4) ? (ty * 4 + i) : (64 + ty * 4 + (i - 4));
            yv[i] = y[(size_t)b * T_ + t0 + tl];
        }
#pragma unroll
        for (int j = 0; j < 8; ++j) {
            float mt = s[0][j];
#pragma unroll
            for (int i = 1; i < 8; ++i) mt = fmaxf(mt, s[i][j]);
            float mn = fmaxf(run_m[j], mt);
            float sc = __expf(run_m[j] - mn);
            float z = run_z[j] * sc, n = run_n[j] * sc;
#pragma unroll
            for (int i = 0; i < 8; ++i) {
                float p = __expf(s[i][j] - mn);
                z += p;
                n = fmaf(p, yv[i], n);
            }
            run_m[j] = mn; run_z[j] = z; run_n[j] = n;
        }
    }
#pragma unroll
    for (int msk = 1; msk < 16; msk <<= 1) {
#pragma unroll
        for (int j = 0; j < 8; ++j) {
            float om = __shfl_xor(run_m[j], msk, 64);
            float oz = __shfl_xor(run_z[j], msk, 64);
            float on = __shfl_xor(run_n[j], msk, 64);
            float mn = fmaxf(run_m[j], om);
            float s0 = __expf(run_m[j] - mn), s1 = __expf(om - mn);
            run_z[j] = fmaf(run_z[j], s0, oz * s1);
            run_n[j] = fmaf(run_n[j], s0, on * s1);
            run_m[j] = mn;
        }
    }
    if (ty == 0) {
#pragma unroll
        for (int j = 0; j < 8; ++j) {
            int ll = (j < 4) ? (tx * 4 + j) : (64 + tx * 4 + (j - 4));
            size_t idx = ((size_t)(b * L_ + lb + ll) * NC + chunk) * 3;
            part[idx + 0] = run_m[j];
            part[idx + 1] = run_z[j];
            part[idx + 2] = run_n[j];
        }
    }
}

__global__ __launch_bounds__(256) void k_comb_f(const float* __restrict__ part,
                                                const float* __restrict__ fc_b,
                                                float* __restrict__ out) {
    int bl = blockIdx.x * 256 + threadIdx.x;
    float m = -1e30f, z = 0.f, n = 0.f;
    for (int c = 0; c < NC; ++c) {
        size_t idx = ((size_t)bl * NC + c) * 3;
        float pm = part[idx + 0], pz = part[idx + 1], pn = part[idx + 2];
        float mn = fmaxf(m, pm);
        float s0 = __expf(m - mn), s1 = __expf(pm - mn);
        z = fmaf(z, s0, pz * s1);
        n = fmaf(n, s0, pn * s1);
        m = mn;
    }
    out[bl] = n / z + fc_b[0];
}

extern "C" void kernel_launch(void* const* d_in, const int* in_sizes, int n_in,
                              void* d_out, int out_size, void* d_ws, size_t ws_size,
                              hipStream_t stream) {
    const float* x    = (const float*)d_in[0];
    const float* q    = (const float*)d_in[1];
    const float* fc_w = (const float*)d_in[2];
    const float* fc_b = (const float*)d_in[3];
    float* out = (float*)d_out;
    float* ws  = (float*)d_ws;

    const size_t Y_F    = (size_t)B_ * T_;
    const size_t PART_F = 3 * PPLANE;
    const size_t PARTF_FALLBACK = (size_t)B_ * L_ * NC * 3;
    const size_t XT_H   = (size_t)B_ * T_ * D_;
    const size_t QT_H   = (size_t)L_ * D_;
    const size_t need   = (Y_F + PART_F) * 4 + (XT_H + QT_H) * 2;

    if (ws_size >= need) {
        float* y    = ws;
        float* part = ws + Y_F;
        _Float16* xt = (_Float16*)(ws + Y_F + PART_F);
        _Float16* qt = xt + XT_H;
        k_prep<<<XBLK + L_ / 16, 256, 0, stream>>>(x, q, fc_w, xt, qt, y);
        k_mfma<<<2048, 256, 0, stream>>>(xt, qt, y, part);
        k_comb_p<<<B_ * L_ / 256, 256, 0, stream>>>(part, fc_b, out);
    } else {
        float* y    = ws;
        float* part = ws + Y_F;
        (void)PARTF_FALLBACK;
        k_y   <<<B_ * T_ / 4, 256, 0, stream>>>(x, fc_w, y);
        k_main<<<dim3(L_ / BL, NC, B_), 256, 0, stream>>>(x, q, y, part);
        k_comb_f<<<B_ * L_ / 256, 256, 0, stream>>>(part, fc_b, out);
    }
}